// Round 2
// baseline (91.576 us; speedup 1.0000x reference)
//
#include <hip/hip_runtime.h>

#define THREADS 512
#define NBLK    1024   // 16384 batches / 16 per block

typedef float v4f    __attribute__((ext_vector_type(4)));
typedef short bf16x8 __attribute__((ext_vector_type(8)));

__constant__ int c_iu[28] = {0,0,0,0,0,0,0,1,1,1,1,1,1,2,2,2,2,2,3,3,3,3,4,4,4,5,5,6};
__constant__ int c_ju[28] = {1,2,3,4,5,6,7,2,3,4,5,6,7,3,4,5,6,7,4,5,6,7,5,6,7,6,7,7};

// LDS layout (bytes). All tiles are K-major bf16 rows of 256B (sProj: 512B),
// XOR-swizzled: byte = row*RB + ((k*2) ^ ((row&7)<<4)).
#define OFF_A    0        // 32KB  sA[128][128]  node bf16      ; reused: sH1[128][128]
#define OFF_GL   32768    // 4KB   sGl[16][128]  global bf16
#define OFF_B1   36864    // 64KB  sB1t[256][128] W1ab^T bf16   ; reused: sProj[128][256]
#define OFF_BG   102400   // 32KB  sBgt[128][128] W1g^T bf16    ; reused: sGp[16][128]
#define OFF_W2   135168   // 16KB  sW2t[64][128]  W2^T bf16
#define OFF_B1V  151552   // 512   b1 f32[128]
#define OFF_B2V  152064   // 256   b2 f32[64]
#define OFF_W3V  152320   // 256   W3 f32[64]
#define SMEM_BYTES 152576

static __device__ __forceinline__ unsigned short f2bf(float f) {
  union { float f; unsigned u; } v; v.f = f;
  return (unsigned short)((v.u + 0x7FFFu + ((v.u >> 16) & 1u)) >> 16);
}
static __device__ __forceinline__ float bf2f(short h) {
  union { unsigned u; float f; } v; v.u = ((unsigned)(unsigned short)h) << 16;
  return v.f;
}

__global__ __launch_bounds__(THREADS, 2)
void docking_fused(const float* __restrict__ node, const float* __restrict__ glob,
                   const int* __restrict__ dmask,
                   const float* __restrict__ W1, const float* __restrict__ b1,
                   const float* __restrict__ W2, const float* __restrict__ b2,
                   const float* __restrict__ W3, const float* __restrict__ b3,
                   float* __restrict__ outp)
{
  __shared__ __align__(16) char smem[SMEM_BYTES];
  const int tid = threadIdx.x;
  const int bb0 = blockIdx.x * 16;            // first batch of this block
  const size_t nrow0 = (size_t)bb0 * 8;       // first node row (128 rows/block)

  // ---------------- stage 0: global -> LDS (bf16, swizzled) ----------------
  // node rows -> sA
  for (int idx = tid; idx < 128 * 16; idx += THREADS) {
    const int r = idx >> 4, ko = idx & 15;
    const float* s = node + (nrow0 + (size_t)r) * 128 + ko * 8;
    const float4 f0 = *(const float4*)(s);
    const float4 f1 = *(const float4*)(s + 4);
    int4 pk;
    pk.x = f2bf(f0.x) | ((unsigned)f2bf(f0.y) << 16);
    pk.y = f2bf(f0.z) | ((unsigned)f2bf(f0.w) << 16);
    pk.z = f2bf(f1.x) | ((unsigned)f2bf(f1.y) << 16);
    pk.w = f2bf(f1.z) | ((unsigned)f2bf(f1.w) << 16);
    *(int4*)(smem + OFF_A + r * 256 + ((ko * 16) ^ ((r & 7) << 4))) = pk;
  }
  // global rows -> sGl
  for (int idx = tid; idx < 16 * 16; idx += THREADS) {
    const int r = idx >> 4, ko = idx & 15;
    const float* s = glob + (size_t)(bb0 + r) * 128 + ko * 8;
    const float4 f0 = *(const float4*)(s);
    const float4 f1 = *(const float4*)(s + 4);
    int4 pk;
    pk.x = f2bf(f0.x) | ((unsigned)f2bf(f0.y) << 16);
    pk.y = f2bf(f0.z) | ((unsigned)f2bf(f0.w) << 16);
    pk.z = f2bf(f1.x) | ((unsigned)f2bf(f1.y) << 16);
    pk.w = f2bf(f1.z) | ((unsigned)f2bf(f1.w) << 16);
    *(int4*)(smem + OFF_GL + r * 256 + ((ko * 16) ^ ((r & 7) << 4))) = pk;
  }
  // W1[0:256] -> sB1t[c][k] (transposed, 2 k's packed per b32 write)
  for (int idx = tid; idx < 16384; idx += THREADS) {
    const int n = idx & 127, kp = (idx >> 7) & 63, part = idx >> 13;
    const float a  = W1[(size_t)(part * 128 + kp * 2    ) * 128 + n];
    const float b_ = W1[(size_t)(part * 128 + kp * 2 + 1) * 128 + n];
    const int c = part * 128 + n;
    const unsigned pk = f2bf(a) | ((unsigned)f2bf(b_) << 16);
    *(unsigned*)(smem + OFF_B1 + c * 256 + ((kp * 4) ^ ((c & 7) << 4))) = pk;
  }
  // W1[256:384] -> sBgt
  for (int idx = tid; idx < 8192; idx += THREADS) {
    const int n = idx & 127, kp = idx >> 7;
    const float a  = W1[(size_t)(256 + kp * 2    ) * 128 + n];
    const float b_ = W1[(size_t)(256 + kp * 2 + 1) * 128 + n];
    const unsigned pk = f2bf(a) | ((unsigned)f2bf(b_) << 16);
    *(unsigned*)(smem + OFF_BG + n * 256 + ((kp * 4) ^ ((n & 7) << 4))) = pk;
  }
  // W2 -> sW2t
  for (int idx = tid; idx < 4096; idx += THREADS) {
    const int n = idx & 63, kp = idx >> 6;
    const float a  = W2[(size_t)(kp * 2    ) * 64 + n];
    const float b_ = W2[(size_t)(kp * 2 + 1) * 64 + n];
    const unsigned pk = f2bf(a) | ((unsigned)f2bf(b_) << 16);
    *(unsigned*)(smem + OFF_W2 + n * 256 + ((kp * 4) ^ ((n & 7) << 4))) = pk;
  }
  if (tid < 128) ((float*)(smem + OFF_B1V))[tid] = b1[tid];
  if (tid < 64)  ((float*)(smem + OFF_B2V))[tid] = b2[tid];
  if (tid < 64)  ((float*)(smem + OFF_W3V))[tid] = W3[tid];
  const float bias3 = *b3;
  __syncthreads();

  // ---------------- phase 1: proj GEMMs (bf16 MFMA) ----------------
  const int wave = tid >> 6, lane = tid & 63;
  const int wm = wave >> 2, wn = wave & 3;     // 2 (M) x 4 (N) wave grid
  const int lrow = lane & 15;
  const int lko  = (lane >> 4) * 8;            // k-elem offset within 32-step

  const v4f vzero = {0.0f, 0.0f, 0.0f, 0.0f};
  v4f acc[4][4];
#pragma unroll
  for (int mt = 0; mt < 4; ++mt)
#pragma unroll
    for (int nt = 0; nt < 4; ++nt) acc[mt][nt] = vzero;
  v4f accg = vzero;

#pragma unroll
  for (int ks = 0; ks < 4; ++ks) {
    const int kb = (ks * 32 + lko) * 2;
    bf16x8 af[4], bfr[4];
#pragma unroll
    for (int mt = 0; mt < 4; ++mt) {
      const int r = wm * 64 + mt * 16 + lrow;
      af[mt] = *(const bf16x8*)(smem + OFF_A + r * 256 + (kb ^ ((r & 7) << 4)));
    }
#pragma unroll
    for (int nt = 0; nt < 4; ++nt) {
      const int c = wn * 64 + nt * 16 + lrow;
      bfr[nt] = *(const bf16x8*)(smem + OFF_B1 + c * 256 + (kb ^ ((c & 7) << 4)));
    }
#pragma unroll
    for (int mt = 0; mt < 4; ++mt)
#pragma unroll
      for (int nt = 0; nt < 4; ++nt)
        acc[mt][nt] = __builtin_amdgcn_mfma_f32_16x16x32_bf16(af[mt], bfr[nt], acc[mt][nt], 0, 0, 0);
    { // global-feature projection: wave w owns c-tile w (16 cols), 16 rows = 16 batches
      const bf16x8 ag = *(const bf16x8*)(smem + OFF_GL + lrow * 256 + (kb ^ ((lrow & 7) << 4)));
      const int cg = wave * 16 + lrow;
      const bf16x8 bg = *(const bf16x8*)(smem + OFF_BG + cg * 256 + (kb ^ ((cg & 7) << 4)));
      accg = __builtin_amdgcn_mfma_f32_16x16x32_bf16(ag, bg, accg, 0, 0, 0);
    }
  }
  __syncthreads();   // done reading sA/sB1t/sBgt; OK to overwrite

  // write proj (bf16) over sB1t region: sProj[m][c], rowBytes 512
#pragma unroll
  for (int mt = 0; mt < 4; ++mt)
#pragma unroll
    for (int nt = 0; nt < 4; ++nt) {
      const int c = wn * 64 + nt * 16 + lrow;
#pragma unroll
      for (int rg = 0; rg < 4; ++rg) {
        const int m = wm * 64 + mt * 16 + (lane >> 4) * 4 + rg;
        *(unsigned short*)(smem + OFF_B1 + m * 512 + ((c * 2) ^ ((m & 7) << 4))) = f2bf(acc[mt][nt][rg]);
      }
    }
  { // write gp (= glob proj + b1) over sBgt region: sGp[bb][c]
    const float* sb1 = (const float*)(smem + OFF_B1V);
    const int c = wave * 16 + lrow;
    const float b1c = sb1[c];
#pragma unroll
    for (int rg = 0; rg < 4; ++rg) {
      const int bbr = (lane >> 4) * 4 + rg;
      *(unsigned short*)(smem + OFF_BG + bbr * 256 + ((c * 2) ^ ((bbr & 7) << 4))) = f2bf(accg[rg] + b1c);
    }
  }
  __syncthreads();

  // ---------------- phase 2/3: pair MLP ----------------
  // preload W2 B-fragments: wave covers ALL 4 n-tiles (n 0..64), in registers
  bf16x8 w2f[4][4];   // [nt][ks]
#pragma unroll
  for (int nt = 0; nt < 4; ++nt)
#pragma unroll
    for (int ks = 0; ks < 4; ++ks) {
      const int c = nt * 16 + lrow;
      const int kb = (ks * 32 + lko) * 2;
      w2f[nt][ks] = *(const bf16x8*)(smem + OFF_W2 + c * 256 + (kb ^ ((c & 7) << 4)));
    }
  float b2n[4], w3n[4];
  {
    const float* sb2 = (const float*)(smem + OFF_B2V);
    const float* sw3 = (const float*)(smem + OFF_W3V);
#pragma unroll
    for (int nt = 0; nt < 4; ++nt) { const int n = nt * 16 + lrow; b2n[nt] = sb2[n]; w3n[nt] = sw3[n]; }
  }

  // 448 pair rows (16 batches x 28), chunks of 128 (last = 64)
  for (int chunk = 0; chunk < 4; ++chunk) {
    const int c0 = chunk * 128;
    const int R = (c0 + 128 <= 448) ? 128 : (448 - c0);
    // build h1 chunk into sH1 (over sA)
    for (int idx = tid; idx < R * 16; idx += THREADS) {
      const int crow = idx >> 4, ko = idx & 15;
      const int pr = c0 + crow;
      const int bb = pr / 28;
      const int p  = pr - bb * 28;
      const int mi = bb * 8 + c_iu[p];
      const int mj = bb * 8 + c_ju[p];
      const bf16x8 va = *(const bf16x8*)(smem + OFF_B1 + mi * 512 + ((ko * 16) ^ ((mi & 7) << 4)));
      const bf16x8 vb = *(const bf16x8*)(smem + OFF_B1 + mj * 512 + (((256 + ko * 16)) ^ ((mj & 7) << 4)));
      const bf16x8 vg = *(const bf16x8*)(smem + OFF_BG + bb * 256 + ((ko * 16) ^ ((bb & 7) << 4)));
      unsigned short h[8];
#pragma unroll
      for (int e = 0; e < 8; ++e)
        h[e] = f2bf(fmaxf(bf2f(va[e]) + bf2f(vb[e]) + bf2f(vg[e]), 0.0f));
      int4 pk;
      pk.x = h[0] | ((unsigned)h[1] << 16);
      pk.y = h[2] | ((unsigned)h[3] << 16);
      pk.z = h[4] | ((unsigned)h[5] << 16);
      pk.w = h[6] | ((unsigned)h[7] << 16);
      *(int4*)(smem + OFF_A + crow * 256 + ((ko * 16) ^ ((crow & 7) << 4))) = pk;
    }
    __syncthreads();

    if (wave * 16 < R) {          // wave owns one 16-row m-tile, all 64 n-cols
      v4f acc2[4];
#pragma unroll
      for (int nt = 0; nt < 4; ++nt) acc2[nt] = vzero;
#pragma unroll
      for (int ks = 0; ks < 4; ++ks) {
        const int r = wave * 16 + lrow;
        const int kb = (ks * 32 + lko) * 2;
        const bf16x8 a2 = *(const bf16x8*)(smem + OFF_A + r * 256 + (kb ^ ((r & 7) << 4)));
#pragma unroll
        for (int nt = 0; nt < 4; ++nt)
          acc2[nt] = __builtin_amdgcn_mfma_f32_16x16x32_bf16(a2, w2f[nt][ks], acc2[nt], 0, 0, 0);
      }
      // epilogue: score = sum_n relu(h2pre + b2) * W3  (+ b3)
      float part[4] = {0.0f, 0.0f, 0.0f, 0.0f};
#pragma unroll
      for (int nt = 0; nt < 4; ++nt)
#pragma unroll
        for (int rg = 0; rg < 4; ++rg)
          part[rg] += fmaxf(acc2[nt][rg] + b2n[nt], 0.0f) * w3n[nt];
#pragma unroll
      for (int mk = 1; mk < 16; mk <<= 1) {
#pragma unroll
        for (int rg = 0; rg < 4; ++rg) part[rg] += __shfl_xor(part[rg], mk, 16);
      }
      if ((lane & 15) == 0) {
        const int rbase = wave * 16 + (lane >> 4) * 4;
#pragma unroll
        for (int rg = 0; rg < 4; ++rg) {
          const int crow = rbase + rg;
          const int pr = c0 + crow;
          const int bb = pr / 28;
          const int p  = pr - bb * 28;
          const size_t o = (size_t)(bb0 + bb) * 28 + p;
          const float sc = part[rg] + bias3;
          outp[o] = dmask[o] ? sc : -1.0e9f;
        }
      }
    }
    __syncthreads();   // protect sH1 before next chunk overwrites
  }
}

extern "C" void kernel_launch(void* const* d_in, const int* in_sizes, int n_in,
                              void* d_out, int out_size, void* d_ws, size_t ws_size,
                              hipStream_t stream) {
  (void)in_sizes; (void)n_in; (void)out_size; (void)d_ws; (void)ws_size;
  const float* node = (const float*)d_in[0];
  const float* glob = (const float*)d_in[1];
  // d_in[2] = group_mask (unused by reference; all-true)
  const int* dmsk   = (const int*)d_in[3];   // bool -> int32 on upload
  // d_in[4] = batch (unused by reference)
  const float* W1 = (const float*)d_in[5];
  const float* b1 = (const float*)d_in[6];
  const float* W2 = (const float*)d_in[7];
  const float* b2 = (const float*)d_in[8];
  const float* W3 = (const float*)d_in[9];
  const float* b3 = (const float*)d_in[10];
  float* outp = (float*)d_out;
  docking_fused<<<NBLK, THREADS, 0, stream>>>(node, glob, dmsk, W1, b1, W2, b2, W3, b3, outp);
}